// Round 6
// baseline (84.588 us; speedup 1.0000x reference)
//
#include <hip/hip_runtime.h>

#define DD 128
#define LL 512
#define BB 2
#define NK (BB * LL)   // 1024 global rows

typedef float v2f __attribute__((ext_vector_type(2)));

// ---- Kernel 1: Es = exp(2*s@W) row-major [NK][DD];
//                EhT4 = exp(2*h@U) tiled [d>>2][key][d&3] (float4-contiguous).
// 256 blocks x 256 thr; 8 rows/block; float4 loads/stores throughout.
__global__ __launch_bounds__(256)
void proj_kernel(const float* __restrict__ s, const float* __restrict__ h,
                 const float* __restrict__ W, const float* __restrict__ U,
                 float* __restrict__ Es, float* __restrict__ EhT4) {
    __shared__ float xr[8 * DD];          // 4 KB: 8 rows, pre-scaled by 2
    int bx = blockIdx.x;                  // 0..255
    bool second = bx >= 128;
    const float* X = second ? h : s;
    const float* M = second ? U : W;
    int row0 = (bx & 127) * 8;
    int t = threadIdx.x;
    {
        float4 xv = *(const float4*)&X[row0 * DD + t * 4];   // coalesced 16B
        xv.x *= 2.f; xv.y *= 2.f; xv.z *= 2.f; xv.w *= 2.f;
        *(float4*)&xr[t * 4] = xv;
    }
    __syncthreads();
    int r = t >> 5, cg = (t & 31) * 4;    // row 0..7, col group
    const float* xrow = &xr[r * DD];
    float4 acc = make_float4(0.f, 0.f, 0.f, 0.f);
#pragma unroll 8
    for (int d = 0; d < DD; ++d) {
        float4 m = *(const float4*)&M[d * DD + cg];   // dwordx4, L2-resident
        float xb = xrow[d];                           // 2-way LDS broadcast (free)
        acc.x = fmaf(xb, m.x, acc.x);
        acc.y = fmaf(xb, m.y, acc.y);
        acc.z = fmaf(xb, m.z, acc.z);
        acc.w = fmaf(xb, m.w, acc.w);
    }
    float4 e;
    e.x = __expf(acc.x); e.y = __expf(acc.y);
    e.z = __expf(acc.z); e.w = __expf(acc.w);
    int row = row0 + r;
    if (!second) {
        *(float4*)&Es[row * DD + cg] = e;
    } else {
        *(float4*)&EhT4[((size_t)(cg >> 2) * NK + row) * 4] = e;  // contiguous f4
    }
}

// ---- Kernel 2: fused attention. Block = 4 queries x all 512 keys, 512 thr.
// Wave w owns keys [w*64,+64), 1 key/lane. Per d-PAIR per query: one rcp,
// packed-fp32 (v_pk_*) arithmetic:
//   v_x/(1+Ex) + v_y/(1+Ey) = [v_x*Ey + v_y*Ex + (v_x+v_y)] / [(1+Ex)(1+Ey)]
// with E = Es(q,d)*Eh(j,d), exps precomputed (no exp in hot loop).
__global__ __launch_bounds__(512, 2)
void attn_kernel(const float* __restrict__ Es, const float* __restrict__ EhT4,
                 const float* __restrict__ h, const float* __restrict__ v,
                 float* __restrict__ out) {
    __shared__ float4 p4[LL];             // p per (key, 4 queries)   8 KB
    __shared__ float4 wsum4[8];           // per-wave exp-sums (4 q)
    __shared__ float red[8][4][DD];       // PV partials             16 KB

    int bx = blockIdx.x;                  // 0..255
    int row0 = bx * 4;                    // global query rows row0..row0+3
    int b = bx >> 7;
    int t = threadIdx.x;
    int lane = t & 63;
    int w = __builtin_amdgcn_readfirstlane(t >> 6);   // uniform wave id

    // ---- phase 1: scores for 4 queries, 1 key per lane ----
    int j = w * 64 + lane;                // key within batch
    int kk = b * LL + j;                  // global key row
    const float4* hp = (const float4*)EhT4 + kk;      // stride NK float4 per d-grp
    const float* es0 = Es + (size_t)row0 * DD;        // uniform -> scalar loads
    v2f ac0 = {0.f, 0.f}, ac1 = {0.f, 0.f}, ac2 = {0.f, 0.f}, ac3 = {0.f, 0.f};
#pragma unroll 4
    for (int dg = 0; dg < 32; ++dg) {
        float4 E  = hp[(size_t)dg * NK];              // Eh, coalesced 1 KB/wave
        float4 q0 = *(const float4*)(es0 + 0 * DD + dg * 4);  // wave-uniform
        float4 q1 = *(const float4*)(es0 + 1 * DD + dg * 4);
        float4 q2 = *(const float4*)(es0 + 2 * DD + dg * 4);
        float4 q3 = *(const float4*)(es0 + 3 * DD + dg * 4);
        float4 vv = *(const float4*)(v + dg * 4);
        v2f Exy = {E.x, E.y},   Ezw = {E.z, E.w};
        v2f vxy = {vv.x, vv.y}, vzw = {vv.z, vv.w};
        float vsxy = vv.x + vv.y;
        float vszw = vv.z + vv.w;
#define PAIRV(es2, Eh2, vv2, vs, ACC)                                     \
        {                                                                 \
            v2f E2 = (es2) * (Eh2);                  /* v_pk_mul_f32 */   \
            v2f d2 = E2 + 1.0f;                      /* v_pk_add_f32 */   \
            float den = d2.x * d2.y;                                      \
            v2f Esw = __builtin_shufflevector(E2, E2, 1, 0);              \
            v2f n2 = (vv2) * Esw;                    /* pk_mul op_sel */  \
            float num = n2.x + n2.y;                                      \
            float rc = __builtin_amdgcn_rcpf(den);                        \
            v2f nv = {num, vs};                                           \
            v2f rr = {rc, rc};                                            \
            ACC = __builtin_elementwise_fma(nv, rr, ACC); /* pk_fma */    \
        }
        PAIRV(((v2f){q0.x, q0.y}), Exy, vxy, vsxy, ac0)
        PAIRV(((v2f){q0.z, q0.w}), Ezw, vzw, vszw, ac0)
        PAIRV(((v2f){q1.x, q1.y}), Exy, vxy, vsxy, ac1)
        PAIRV(((v2f){q1.z, q1.w}), Ezw, vzw, vszw, ac1)
        PAIRV(((v2f){q2.x, q2.y}), Exy, vxy, vsxy, ac2)
        PAIRV(((v2f){q2.z, q2.w}), Ezw, vzw, vszw, ac2)
        PAIRV(((v2f){q3.x, q3.y}), Exy, vxy, vsxy, ac3)
        PAIRV(((v2f){q3.z, q3.w}), Ezw, vzw, vszw, ac3)
#undef PAIRV
    }
    // score = sum_d v_d*tanh = (const) - 2*acc; const is softmax-invariant.
    float p0 = __expf(-2.f * (ac0.x + ac0.y));
    float p1 = __expf(-2.f * (ac1.x + ac1.y));
    float p2 = __expf(-2.f * (ac2.x + ac2.y));
    float p3 = __expf(-2.f * (ac3.x + ac3.y));
    p4[j] = make_float4(p0, p1, p2, p3);
    float m0 = p0, m1 = p1, m2 = p2, m3 = p3;
#pragma unroll
    for (int o = 1; o < 64; o <<= 1) {
        m0 += __shfl_xor(m0, o);
        m1 += __shfl_xor(m1, o);
        m2 += __shfl_xor(m2, o);
        m3 += __shfl_xor(m3, o);
    }
    if (lane == 0) wsum4[w] = make_float4(m0, m1, m2, m3);
    __syncthreads();

    // ---- phase 3: PV. Wave w keys [w*64,+64), 2 keys/iter (halves), lane d4.
    int half = lane >> 5;
    int d4 = (lane & 31) * 4;
    const float* hb = h + (size_t)b * LL * DD;
    float4 A0 = make_float4(0.f, 0.f, 0.f, 0.f), A1 = A0, A2 = A0, A3 = A0;
#pragma unroll 4
    for (int jj = 0; jj < 32; ++jj) {
        int jl = w * 64 + jj * 2 + half;
        float4 hv = *(const float4*)&hb[jl * DD + d4];   // contiguous 1 KB/wave
        float4 pp = p4[jl];                               // b128 broadcast
        A0.x = fmaf(pp.x, hv.x, A0.x); A0.y = fmaf(pp.x, hv.y, A0.y);
        A0.z = fmaf(pp.x, hv.z, A0.z); A0.w = fmaf(pp.x, hv.w, A0.w);
        A1.x = fmaf(pp.y, hv.x, A1.x); A1.y = fmaf(pp.y, hv.y, A1.y);
        A1.z = fmaf(pp.y, hv.z, A1.z); A1.w = fmaf(pp.y, hv.w, A1.w);
        A2.x = fmaf(pp.z, hv.x, A2.x); A2.y = fmaf(pp.z, hv.y, A2.y);
        A2.z = fmaf(pp.z, hv.z, A2.z); A2.w = fmaf(pp.z, hv.w, A2.w);
        A3.x = fmaf(pp.w, hv.x, A3.x); A3.y = fmaf(pp.w, hv.y, A3.y);
        A3.z = fmaf(pp.w, hv.z, A3.z); A3.w = fmaf(pp.w, hv.w, A3.w);
    }
#define FOLD(A) A.x += __shfl_xor(A.x, 32); A.y += __shfl_xor(A.y, 32); \
                A.z += __shfl_xor(A.z, 32); A.w += __shfl_xor(A.w, 32);
    FOLD(A0) FOLD(A1) FOLD(A2) FOLD(A3)
#undef FOLD
    if (half == 0) {
        *(float4*)&red[w][0][d4] = A0;
        *(float4*)&red[w][1][d4] = A1;
        *(float4*)&red[w][2][d4] = A2;
        *(float4*)&red[w][3][d4] = A3;
    }
    __syncthreads();

    // ---- epilogue: sum 8 wave-partials, normalize, store ----
    {
        int q = t >> 7, d = t & 127;
        float o = 0.f;
#pragma unroll
        for (int k = 0; k < 8; ++k) o += red[k][q][d];
        const float* wf = (const float*)wsum4;
        float qs = 0.f;
#pragma unroll
        for (int k = 0; k < 8; ++k) qs += wf[k * 4 + q];
        out[(size_t)(row0 + q) * DD + d] = o * __builtin_amdgcn_rcpf(qs);
    }
}

extern "C" void kernel_launch(void* const* d_in, const int* in_sizes, int n_in,
                              void* d_out, int out_size, void* d_ws, size_t ws_size,
                              hipStream_t stream) {
    const float* s = (const float*)d_in[0];
    const float* h = (const float*)d_in[1];
    const float* W = (const float*)d_in[2];
    const float* U = (const float*)d_in[3];
    const float* v = (const float*)d_in[4];
    float* out = (float*)d_out;
    float* ws  = (float*)d_ws;

    float* Es   = ws;                     // 1024*128 floats: exp(2*s@W)
    float* EhT4 = ws + 131072;            // 1024*128 floats: exp(2*h@U), tiled

    hipLaunchKernelGGL(proj_kernel, dim3(256), dim3(256), 0, stream,
                       s, h, W, U, Es, EhT4);
    hipLaunchKernelGGL(attn_kernel, dim3(NK / 4), dim3(512), 0, stream,
                       Es, EhT4, h, v, out);
}